// Round 1
// baseline (223.076 us; speedup 1.0000x reference)
//
#include <hip/hip_runtime.h>
#include <hip/hip_bf16.h>
#include <math.h>

// Problem constants (from setup_inputs):
//   B=8, T=64 (n_tok), R=100 (n_RoI), TH=768, IH=1024, P=512
#define B_  8
#define T_  64
#define R_  100
#define TH_ 768
#define IH_ 1024
#define P_  512

// ---------------------------------------------------------------------------
// Tiled fp32 GEMM + bias + exact GELU:  Y[M,N] = gelu(X[M,K] @ W[K,N] + bias)
// TS=32 tile, BK=32, 256 threads, each thread 2x2 outputs.
// All of M (512, 800), K (768, 1024), N (512) are divisible by 32 -> no guards.
// ---------------------------------------------------------------------------
#define TS 32

__global__ __launch_bounds__(256) void linear_gelu_kernel(
    const float* __restrict__ X, const float* __restrict__ W,
    const float* __restrict__ bias, float* __restrict__ Y,
    int M, int K, int N) {
  __shared__ float Xs[TS][TS + 1];
  __shared__ float Ws[TS][TS + 1];

  const int tx = threadIdx.x & 15;        // 0..15 (col within tile)
  const int ty = threadIdx.x >> 4;        // 0..15 (row within tile)
  const int row0 = blockIdx.y * TS;
  const int col0 = blockIdx.x * TS;

  float acc00 = 0.f, acc01 = 0.f, acc10 = 0.f, acc11 = 0.f;

  for (int k0 = 0; k0 < K; k0 += TS) {
    // cooperative load: 32x32 = 1024 elems each, 256 threads -> 4 elems each
    #pragma unroll
    for (int i = 0; i < 4; ++i) {
      int idx = threadIdx.x + i * 256;
      int r = idx >> 5, c = idx & 31;
      Xs[r][c] = X[(size_t)(row0 + r) * K + (k0 + c)];
      Ws[r][c] = W[(size_t)(k0 + r) * N + (col0 + c)];
    }
    __syncthreads();
    #pragma unroll
    for (int kk = 0; kk < TS; ++kk) {
      float x0 = Xs[ty][kk];
      float x1 = Xs[ty + 16][kk];
      float w0 = Ws[kk][tx];
      float w1 = Ws[kk][tx + 16];
      acc00 += x0 * w0; acc01 += x0 * w1;
      acc10 += x1 * w0; acc11 += x1 * w1;
    }
    __syncthreads();
  }

  // epilogue: bias + exact GELU  (0.5*x*(1+erf(x/sqrt(2))))
  const float inv_sqrt2 = 0.70710678118654752f;
  float b0 = bias[col0 + tx];
  float b1 = bias[col0 + tx + 16];

  float v;
  v = acc00 + b0; v = 0.5f * v * (1.f + erff(v * inv_sqrt2));
  Y[(size_t)(row0 + ty) * N + (col0 + tx)] = v;
  v = acc01 + b1; v = 0.5f * v * (1.f + erff(v * inv_sqrt2));
  Y[(size_t)(row0 + ty) * N + (col0 + tx + 16)] = v;
  v = acc10 + b0; v = 0.5f * v * (1.f + erff(v * inv_sqrt2));
  Y[(size_t)(row0 + ty + 16) * N + (col0 + tx)] = v;
  v = acc11 + b1; v = 0.5f * v * (1.f + erff(v * inv_sqrt2));
  Y[(size_t)(row0 + ty + 16) * N + (col0 + tx + 16)] = v;
}

// ---------------------------------------------------------------------------
// Fusion: out[b,t,r] = sum_p tanh(q[b,t,p] + k[b,r,p]) * w[p] + bias + mask[b,t,r]
// One block per (b,t) = 512 blocks, 256 threads = 4 waves.
// q row (2 KB) + w (2 KB) staged in LDS; each wave handles r = wave, wave+4, ...
// ---------------------------------------------------------------------------
__global__ __launch_bounds__(256) void fuse_kernel(
    const float* __restrict__ q, const float* __restrict__ k,
    const float* __restrict__ w, const float* __restrict__ bscalar,
    const float* __restrict__ mask, float* __restrict__ out) {
  const int bt = blockIdx.x;        // 0..511
  const int b = bt >> 6;            // batch

  __shared__ float qs[P_];
  __shared__ float ws[P_];
  for (int i = threadIdx.x; i < P_; i += 256) {
    qs[i] = q[(size_t)bt * P_ + i];
    ws[i] = w[i];
  }
  __syncthreads();

  const int wave = threadIdx.x >> 6;
  const int lane = threadIdx.x & 63;
  const float bval = bscalar[0];

  for (int r = wave; r < R_; r += 4) {
    const float* __restrict__ krow = k + (size_t)(b * R_ + r) * P_;
    float acc = 0.f;
    #pragma unroll
    for (int j = 0; j < P_ / 64; ++j) {
      int p = j * 64 + lane;
      acc += tanhf(qs[p] + krow[p]) * ws[p];
    }
    // 64-lane butterfly reduce
    #pragma unroll
    for (int off = 32; off > 0; off >>= 1) acc += __shfl_down(acc, off, 64);
    if (lane == 0) {
      out[(size_t)bt * R_ + r] = acc + bval + mask[(size_t)bt * R_ + r];
    }
  }
}

// ---------------------------------------------------------------------------
extern "C" void kernel_launch(void* const* d_in, const int* in_sizes, int n_in,
                              void* d_out, int out_size, void* d_ws, size_t ws_size,
                              hipStream_t stream) {
  const float* encT = (const float*)d_in[0];  // [B,T,TH]
  const float* encI = (const float*)d_in[1];  // [B,R,IH]
  const float* mask = (const float*)d_in[2];  // [B,1,T,R]
  const float* Wq   = (const float*)d_in[3];  // [TH,P]
  const float* bq   = (const float*)d_in[4];  // [P]
  const float* Wk   = (const float*)d_in[5];  // [IH,P]
  const float* bk   = (const float*)d_in[6];  // [P]
  const float* w    = (const float*)d_in[7];  // [P]
  const float* bsc  = (const float*)d_in[8];  // [1]
  float* out = (float*)d_out;                 // [B,T,R]

  float* q = (float*)d_ws;                    // [B*T, P]  = 512*512 floats (1 MB)
  float* k = q + (size_t)B_ * T_ * P_;        // [B*R, P]  = 800*512 floats (1.6 MB)

  // Q = gelu(encT @ Wq + bq): M=512, K=768, N=512
  {
    dim3 grid(P_ / TS, (B_ * T_) / TS);       // (16, 16)
    linear_gelu_kernel<<<grid, 256, 0, stream>>>(encT, Wq, bq, q, B_ * T_, TH_, P_);
  }
  // K = gelu(encI @ Wk + bk): M=800, K=1024, N=512
  {
    dim3 grid(P_ / TS, (B_ * R_) / TS);       // (16, 25)
    linear_gelu_kernel<<<grid, 256, 0, stream>>>(encI, Wk, bk, k, B_ * R_, IH_, P_);
  }
  // Fusion
  fuse_kernel<<<dim3(B_ * T_), 256, 0, stream>>>(q, k, w, bsc, mask, out);
}

// Round 2
// 129.299 us; speedup vs baseline: 1.7253x; 1.7253x over previous
//
#include <hip/hip_runtime.h>
#include <math.h>

// Problem constants: B=8, T=64, R=100, TH=768, IH=1024, P=N=512
#define B_  8
#define T_  64
#define R_  100
#define TH_ 768
#define IH_ 1024
#define P_  512
#define N_  512

// ---------------------------------------------------------------------------
// GEMM + bias + exact GELU, 64x64 tile, BK=16, 256 threads, 4x4 per thread,
// register prefetch of next K-tile. Both GEMMs in ONE launch (grid.y split).
// ---------------------------------------------------------------------------
#define BM 64
#define BN 64
#define BK 16

template<int KDIM>
__device__ __forceinline__ void gemm_tile(
    const float* __restrict__ X, const float* __restrict__ W,
    const float* __restrict__ bias, float* __restrict__ Y,
    int M, int row0, int col0) {
  __shared__ float As[BK][BM + 4];   // transposed A tile: As[k][m]
  __shared__ float Bs[BK][BN + 4];   // Bs[k][n]

  const int tid = threadIdx.x;
  const int tx = tid & 15;          // n-group (4 cols)
  const int ty = tid >> 4;          // m-group (4 rows)

  // loader indices
  const int am = tid >> 2;          // 0..63 (row within A tile)
  const int ak = (tid & 3) * 4;     // 0,4,8,12
  const int bkr = tid >> 4;         // 0..15 (k row of B tile)
  const int bn = (tid & 15) * 4;    // 0..60

  const int arow = min(row0 + am, M - 1);   // clamp for M=800 edge tiles
  const float* __restrict__ Xp = X + (size_t)arow * KDIM;
  const float* __restrict__ Wp = W + (size_t)bkr * N_ + col0 + bn;

  float acc[4][4];
  #pragma unroll
  for (int i = 0; i < 4; ++i)
    #pragma unroll
    for (int j = 0; j < 4; ++j) acc[i][j] = 0.f;

  float4 av = *(const float4*)(Xp + ak);
  float4 bv = *(const float4*)(Wp);

  for (int k0 = 0; k0 < KDIM; k0 += BK) {
    As[ak + 0][am] = av.x;
    As[ak + 1][am] = av.y;
    As[ak + 2][am] = av.z;
    As[ak + 3][am] = av.w;
    *(float4*)&Bs[bkr][bn] = bv;
    __syncthreads();

    if (k0 + BK < KDIM) {               // prefetch next tile into registers
      av = *(const float4*)(Xp + k0 + BK + ak);
      bv = *(const float4*)(Wp + (size_t)BK * N_ + (size_t)(k0 / BK) * BK * N_ - (size_t)(k0 / BK) * BK * N_ + (size_t)k0 * 0);
      // (address recomputed cleanly below)
      bv = *(const float4*)(W + (size_t)(k0 + BK + bkr) * N_ + col0 + bn);
    }

    #pragma unroll
    for (int kk = 0; kk < BK; ++kk) {
      float4 a0 = *(const float4*)&As[kk][ty * 4];
      float4 b0 = *(const float4*)&Bs[kk][tx * 4];
      acc[0][0] = fmaf(a0.x, b0.x, acc[0][0]);
      acc[0][1] = fmaf(a0.x, b0.y, acc[0][1]);
      acc[0][2] = fmaf(a0.x, b0.z, acc[0][2]);
      acc[0][3] = fmaf(a0.x, b0.w, acc[0][3]);
      acc[1][0] = fmaf(a0.y, b0.x, acc[1][0]);
      acc[1][1] = fmaf(a0.y, b0.y, acc[1][1]);
      acc[1][2] = fmaf(a0.y, b0.z, acc[1][2]);
      acc[1][3] = fmaf(a0.y, b0.w, acc[1][3]);
      acc[2][0] = fmaf(a0.z, b0.x, acc[2][0]);
      acc[2][1] = fmaf(a0.z, b0.y, acc[2][1]);
      acc[2][2] = fmaf(a0.z, b0.z, acc[2][2]);
      acc[2][3] = fmaf(a0.z, b0.w, acc[2][3]);
      acc[3][0] = fmaf(a0.w, b0.x, acc[3][0]);
      acc[3][1] = fmaf(a0.w, b0.y, acc[3][1]);
      acc[3][2] = fmaf(a0.w, b0.z, acc[3][2]);
      acc[3][3] = fmaf(a0.w, b0.w, acc[3][3]);
    }
    __syncthreads();
  }

  // epilogue: bias + exact GELU, float4 stores
  const float inv_sqrt2 = 0.70710678118654752f;
  const int col = col0 + tx * 4;
  float4 bb = *(const float4*)(bias + col);
  #pragma unroll
  for (int i = 0; i < 4; ++i) {
    int row = row0 + ty * 4 + i;
    if (row < M) {
      float4 o;
      float v;
      v = acc[i][0] + bb.x; o.x = 0.5f * v * (1.f + erff(v * inv_sqrt2));
      v = acc[i][1] + bb.y; o.y = 0.5f * v * (1.f + erff(v * inv_sqrt2));
      v = acc[i][2] + bb.z; o.z = 0.5f * v * (1.f + erff(v * inv_sqrt2));
      v = acc[i][3] + bb.w; o.w = 0.5f * v * (1.f + erff(v * inv_sqrt2));
      *(float4*)(Y + (size_t)row * N_ + col) = o;
    }
  }
}

__global__ __launch_bounds__(256) void dual_linear_gelu(
    const float* __restrict__ encT, const float* __restrict__ Wq,
    const float* __restrict__ bq, float* __restrict__ qout,
    const float* __restrict__ encI, const float* __restrict__ Wk,
    const float* __restrict__ bk, float* __restrict__ kout) {
  const int col0 = blockIdx.x * BN;
  if (blockIdx.y < 8) {
    // Q gemm: M=512, K=768
    gemm_tile<TH_>(encT, Wq, bq, qout, B_ * T_, blockIdx.y * BM, col0);
  } else {
    // K gemm: M=800, K=1024  (13 row-tiles, last partially full)
    gemm_tile<IH_>(encI, Wk, bk, kout, B_ * R_, (blockIdx.y - 8) * BM, col0);
  }
}

// ---------------------------------------------------------------------------
// Fusion: out[b,t,r] = sum_p tanh(q+k)*w + b + mask
//       = sumw - 2*sum_p w[p]/(1+exp2(C*(q+k))) + b + mask
// Block per (b,t); 4 waves; each wave-pass covers 4 r's with 16 lanes each.
// q,w slices live in registers; inner loop = float4 k-load + 6 VALU/elem.
// ---------------------------------------------------------------------------
__global__ __launch_bounds__(256) void fuse_kernel(
    const float* __restrict__ q, const float* __restrict__ k,
    const float* __restrict__ w, const float* __restrict__ bscalar,
    const float* __restrict__ mask, float* __restrict__ out) {
  const int bt = blockIdx.x;         // 0..511
  const int b  = bt >> 6;
  const int wave = threadIdx.x >> 6; // 0..3
  const int lane = threadIdx.x & 63;
  const int sub  = lane >> 4;        // which r within group of 4
  const int pi   = lane & 15;        // p-slice index

  // preload q and w slices: lane covers p = i*64 + pi*4 .. +3, i=0..7
  float4 qv[8], wv[8];
  const float* __restrict__ qrow = q + (size_t)bt * P_;
  #pragma unroll
  for (int i = 0; i < 8; ++i) {
    qv[i] = *(const float4*)(qrow + i * 64 + pi * 4);
    wv[i] = *(const float4*)(w + i * 64 + pi * 4);
  }
  float sumw = 0.f;
  #pragma unroll
  for (int i = 0; i < 8; ++i) sumw += wv[i].x + wv[i].y + wv[i].z + wv[i].w;
  #pragma unroll
  for (int off = 1; off < 16; off <<= 1) sumw += __shfl_xor(sumw, off, 64);

  const float C = 2.88539008177792681f;   // 2*log2(e)
  const float bval = bscalar[0];

  for (int rg = wave; rg < 25; rg += 4) {
    const int r = rg * 4 + sub;          // < 100 always (25*4 = 100)
    const float* __restrict__ krow = k + (size_t)(b * R_ + r) * P_;
    float su = 0.f;
    #pragma unroll
    for (int i = 0; i < 8; ++i) {
      float4 kv = *(const float4*)(krow + i * 64 + pi * 4);
      float x, e, u;
      x = qv[i].x + kv.x;
      e = __builtin_amdgcn_exp2f(x * C);
      u = __builtin_amdgcn_rcpf(1.f + e);
      su = fmaf(wv[i].x, u, su);
      x = qv[i].y + kv.y;
      e = __builtin_amdgcn_exp2f(x * C);
      u = __builtin_amdgcn_rcpf(1.f + e);
      su = fmaf(wv[i].y, u, su);
      x = qv[i].z + kv.z;
      e = __builtin_amdgcn_exp2f(x * C);
      u = __builtin_amdgcn_rcpf(1.f + e);
      su = fmaf(wv[i].z, u, su);
      x = qv[i].w + kv.w;
      e = __builtin_amdgcn_exp2f(x * C);
      u = __builtin_amdgcn_rcpf(1.f + e);
      su = fmaf(wv[i].w, u, su);
    }
    #pragma unroll
    for (int off = 1; off < 16; off <<= 1) su += __shfl_xor(su, off, 64);
    if (pi == 0) {
      out[(size_t)bt * R_ + r] = sumw - 2.f * su + bval + mask[(size_t)bt * R_ + r];
    }
  }
}

// ---------------------------------------------------------------------------
extern "C" void kernel_launch(void* const* d_in, const int* in_sizes, int n_in,
                              void* d_out, int out_size, void* d_ws, size_t ws_size,
                              hipStream_t stream) {
  const float* encT = (const float*)d_in[0];
  const float* encI = (const float*)d_in[1];
  const float* mask = (const float*)d_in[2];
  const float* Wq   = (const float*)d_in[3];
  const float* bq   = (const float*)d_in[4];
  const float* Wk   = (const float*)d_in[5];
  const float* bk   = (const float*)d_in[6];
  const float* w    = (const float*)d_in[7];
  const float* bsc  = (const float*)d_in[8];
  float* out = (float*)d_out;

  float* q = (float*)d_ws;                 // [512, 512]
  float* k = q + (size_t)B_ * T_ * P_;     // [800, 512]

  // Both GEMMs in one launch: grid.y 0..7 -> Q (8 row tiles), 8..20 -> K (13)
  dim3 grid(N_ / BN, 8 + 13);
  dual_linear_gelu<<<grid, 256, 0, stream>>>(encT, Wq, bq, q, encI, Wk, bk, k);

  fuse_kernel<<<dim3(B_ * T_), 256, 0, stream>>>(q, k, w, bsc, mask, out);
}

// Round 4
// 104.958 us; speedup vs baseline: 2.1254x; 1.2319x over previous
//
#include <hip/hip_runtime.h>
#include <math.h>

// Problem constants: B=8, T=64, R=100, TH=768, IH=1024, P=N=512
#define B_  8
#define T_  64
#define R_  100
#define TH_ 768
#define IH_ 1024
#define P_  512
#define N_  512

#define CTANH 2.88539008177792681f   // 2*log2(e): tanh(x) = 1 - 2/(1+exp2(CTANH*x))

typedef short short8  __attribute__((ext_vector_type(8)));
typedef float floatx4 __attribute__((ext_vector_type(4)));

__device__ __forceinline__ ushort f2bf(float f) {
  union { float f; unsigned int u; } v; v.f = f;
  unsigned int r = v.u + 0x7FFFu + ((v.u >> 16) & 1u);   // RNE
  return (ushort)(r >> 16);
}

// ---------------------------------------------------------------------------
// MFMA bf16 GEMM + bias + exact GELU (output pre-scaled by CTANH).
// Grid (8 col-tiles, 21 row-tiles: 0..7 Q [M=512,K=768], 8..20 K [M=800,K=1024]).
// 64x64 tile, BK=32, 256 threads = 4 waves; each wave one 32x32 quadrant via
// 2x2 mfma_f32_16x16x32_bf16. f32 inputs converted to bf16 during LDS staging.
// LDS: As[m][k] (A row-major), Bs[n][k] (B transposed) — both frag reads are
// contiguous ds_read_b128. Rows padded to 40 bf16 (80 B: 16B-aligned, bank
// stride 20 -> <=2-way conflicts, free per m136).
// ---------------------------------------------------------------------------
#define PADK 40

__global__ __launch_bounds__(256) void mfma_linear_gelu(
    const float* __restrict__ encT, const float* __restrict__ Wq,
    const float* __restrict__ bq, float* __restrict__ qout,
    const float* __restrict__ encI, const float* __restrict__ Wk,
    const float* __restrict__ bk, float* __restrict__ kout) {
  const int rt = blockIdx.y;
  const bool isQ = rt < 8;
  const float* __restrict__ X = isQ ? encT : encI;
  const float* __restrict__ W = isQ ? Wq : Wk;
  const float* __restrict__ bias = isQ ? bq : bk;
  float* __restrict__ Y = isQ ? qout : kout;
  const int M    = isQ ? (B_ * T_) : (B_ * R_);
  const int KDIM = isQ ? TH_ : IH_;
  const int row0 = (isQ ? rt : (rt - 8)) * 64;
  const int col0 = blockIdx.x * 64;
  const int ntiles = KDIM / 32;            // 24 (Q) or 32 (K)

  __shared__ ushort As[64 * PADK];         // As[m*PADK + k]
  __shared__ ushort Bs[64 * PADK];         // Bs[n*PADK + k]  (transposed B)

  const int tid = threadIdx.x;

  // --- A loader: thread covers row (tid>>2), k-chunk (tid&3)*8 .. +7 ---
  const int arow = tid >> 2;               // 0..63
  const int akq  = (tid & 3) * 8;          // 0,8,16,24
  const int arowc = min(row0 + arow, M - 1);
  const float* __restrict__ Xp = X + (size_t)arowc * KDIM + akq;

  // --- B loader: thread covers k-pair (tid>>4)*2, n-chunk (tid&15)*4 ---
  const int bkp = (tid >> 4) * 2;          // 0,2,..,30
  const int bn4 = (tid & 15) * 4;          // 0,4,..,60
  const float* __restrict__ Wp = W + (size_t)bkp * N_ + col0 + bn4;

  // --- compute mapping: wave quadrant ---
  const int wave = tid >> 6;               // 0..3
  const int lane = tid & 63;
  const int wm = (wave >> 1) * 32;         // row offset of wave's 32x32
  const int wn = (wave & 1) * 32;          // col offset
  const int l15 = lane & 15;
  const int q8  = (lane >> 4) * 8;

  floatx4 acc00 = {0.f,0.f,0.f,0.f}, acc01 = {0.f,0.f,0.f,0.f};
  floatx4 acc10 = {0.f,0.f,0.f,0.f}, acc11 = {0.f,0.f,0.f,0.f};

  // register prefetch of tile 0
  float4 a0 = *(const float4*)(Xp + 0);
  float4 a1 = *(const float4*)(Xp + 4);
  float4 b0 = *(const float4*)(Wp);
  float4 b1 = *(const float4*)(Wp + N_);

  for (int kt = 0; kt < ntiles; ++kt) {
    // stage A: 8 bf16 contiguous in k -> one ds_write_b128
    {
      short8 pk;
      pk[0] = (short)f2bf(a0.x); pk[1] = (short)f2bf(a0.y);
      pk[2] = (short)f2bf(a0.z); pk[3] = (short)f2bf(a0.w);
      pk[4] = (short)f2bf(a1.x); pk[5] = (short)f2bf(a1.y);
      pk[6] = (short)f2bf(a1.z); pk[7] = (short)f2bf(a1.w);
      *(short8*)&As[arow * PADK + akq] = pk;
    }
    // stage B transposed: pairs (k, k+1) contiguous -> four 4B writes
    {
      unsigned int p0 = (unsigned int)f2bf(b0.x) | ((unsigned int)f2bf(b1.x) << 16);
      unsigned int p1 = (unsigned int)f2bf(b0.y) | ((unsigned int)f2bf(b1.y) << 16);
      unsigned int p2 = (unsigned int)f2bf(b0.z) | ((unsigned int)f2bf(b1.z) << 16);
      unsigned int p3 = (unsigned int)f2bf(b0.w) | ((unsigned int)f2bf(b1.w) << 16);
      *(unsigned int*)&Bs[(bn4 + 0) * PADK + bkp] = p0;
      *(unsigned int*)&Bs[(bn4 + 1) * PADK + bkp] = p1;
      *(unsigned int*)&Bs[(bn4 + 2) * PADK + bkp] = p2;
      *(unsigned int*)&Bs[(bn4 + 3) * PADK + bkp] = p3;
    }
    __syncthreads();

    // prefetch next tile while computing
    if (kt + 1 < ntiles) {
      const int kb = (kt + 1) * 32;
      a0 = *(const float4*)(Xp + kb);
      a1 = *(const float4*)(Xp + kb + 4);
      b0 = *(const float4*)(W + (size_t)(kb + bkp) * N_ + col0 + bn4);
      b1 = *(const float4*)(W + (size_t)(kb + bkp + 1) * N_ + col0 + bn4);
    }

    // frag loads (contiguous 16B) + 2x2 MFMA
    short8 af0 = *(const short8*)&As[(wm + l15) * PADK + q8];
    short8 af1 = *(const short8*)&As[(wm + 16 + l15) * PADK + q8];
    short8 bf0 = *(const short8*)&Bs[(wn + l15) * PADK + q8];
    short8 bf1 = *(const short8*)&Bs[(wn + 16 + l15) * PADK + q8];
    acc00 = __builtin_amdgcn_mfma_f32_16x16x32_bf16(af0, bf0, acc00, 0, 0, 0);
    acc01 = __builtin_amdgcn_mfma_f32_16x16x32_bf16(af0, bf1, acc01, 0, 0, 0);
    acc10 = __builtin_amdgcn_mfma_f32_16x16x32_bf16(af1, bf0, acc10, 0, 0, 0);
    acc11 = __builtin_amdgcn_mfma_f32_16x16x32_bf16(af1, bf1, acc11, 0, 0, 0);
    __syncthreads();
  }

  // epilogue: D layout row=(lane>>4)*4+reg, col=lane&15 (m89-verified).
  const float is2 = 0.70710678118654752f;
  const float bia0 = bias[col0 + wn + l15];
  const float bia1 = bias[col0 + wn + 16 + l15];
  const int rbase = row0 + wm + (lane >> 4) * 4;

  #pragma unroll
  for (int r = 0; r < 4; ++r) {
    // m-subtile 0 rows
    int row = rbase + r;
    if (row < M) {
      float v0 = acc00[r] + bia0;
      Y[(size_t)row * N_ + col0 + wn + l15] =
          CTANH * 0.5f * v0 * (1.f + erff(v0 * is2));
      float v1 = acc01[r] + bia1;
      Y[(size_t)row * N_ + col0 + wn + 16 + l15] =
          CTANH * 0.5f * v1 * (1.f + erff(v1 * is2));
    }
    // m-subtile 1 rows
    int row2 = rbase + 16 + r;
    if (row2 < M) {
      float v2 = acc10[r] + bia0;
      Y[(size_t)row2 * N_ + col0 + wn + l15] =
          CTANH * 0.5f * v2 * (1.f + erff(v2 * is2));
      float v3 = acc11[r] + bia1;
      Y[(size_t)row2 * N_ + col0 + wn + 16 + l15] =
          CTANH * 0.5f * v3 * (1.f + erff(v3 * is2));
    }
  }
}

// ---------------------------------------------------------------------------
// Fusion: out[b,t,r] = sumw - 2*sum_p w[p]/(1+exp2(q'+k')) + b + mask
// (q', k' pre-scaled by CTANH). Grid (512 bt, 2 r-halves), 256 threads.
// Per wave: 4 r's concurrently (16 lanes each, 32 elems/lane), 2 acc chains.
// ---------------------------------------------------------------------------
__global__ __launch_bounds__(256) void fuse_kernel(
    const float* __restrict__ q, const float* __restrict__ k,
    const float* __restrict__ w, const float* __restrict__ bscalar,
    const float* __restrict__ mask, float* __restrict__ out) {
  const int bt = blockIdx.x;          // 0..511
  const int half = blockIdx.y;        // 0..1 -> rg [0,12) or [12,25)
  const int b  = bt >> 6;
  const int wave = threadIdx.x >> 6;
  const int lane = threadIdx.x & 63;
  const int sub  = lane >> 4;         // r within group of 4
  const int pi   = lane & 15;         // p-slice

  float4 qv[8], wv[8];
  const float* __restrict__ qrow = q + (size_t)bt * P_;
  #pragma unroll
  for (int i = 0; i < 8; ++i) {
    qv[i] = *(const float4*)(qrow + i * 64 + pi * 4);
    wv[i] = *(const float4*)(w + i * 64 + pi * 4);
  }
  float sumw = 0.f;
  #pragma unroll
  for (int i = 0; i < 8; ++i) sumw += wv[i].x + wv[i].y + wv[i].z + wv[i].w;
  #pragma unroll
  for (int off = 1; off < 16; off <<= 1) sumw += __shfl_xor(sumw, off, 64);

  const float bval = bscalar[0];
  const int rg_beg = half ? 12 : 0;
  const int rg_end = half ? 25 : 12;

  for (int rg = rg_beg + wave; rg < rg_end; rg += 4) {
    const int r = rg * 4 + sub;
    const float* __restrict__ krow = k + (size_t)(b * R_ + r) * P_;
    float su0 = 0.f, su1 = 0.f;
    #pragma unroll
    for (int i = 0; i < 8; ++i) {
      float4 kv = *(const float4*)(krow + i * 64 + pi * 4);
      float x, e, u;
      x = qv[i].x + kv.x;
      e = __builtin_amdgcn_exp2f(x);
      u = __builtin_amdgcn_rcpf(1.f + e);
      su0 = fmaf(wv[i].x, u, su0);
      x = qv[i].y + kv.y;
      e = __builtin_amdgcn_exp2f(x);
      u = __builtin_amdgcn_rcpf(1.f + e);
      su1 = fmaf(wv[i].y, u, su1);
      x = qv[i].z + kv.z;
      e = __builtin_amdgcn_exp2f(x);
      u = __builtin_amdgcn_rcpf(1.f + e);
      su0 = fmaf(wv[i].z, u, su0);
      x = qv[i].w + kv.w;
      e = __builtin_amdgcn_exp2f(x);
      u = __builtin_amdgcn_rcpf(1.f + e);
      su1 = fmaf(wv[i].w, u, su1);
    }
    float su = su0 + su1;
    #pragma unroll
    for (int off = 1; off < 16; off <<= 1) su += __shfl_xor(su, off, 64);
    if (pi == 0) {
      out[(size_t)bt * R_ + r] = sumw - 2.f * su + bval + mask[(size_t)bt * R_ + r];
    }
  }
}

// ---------------------------------------------------------------------------
extern "C" void kernel_launch(void* const* d_in, const int* in_sizes, int n_in,
                              void* d_out, int out_size, void* d_ws, size_t ws_size,
                              hipStream_t stream) {
  const float* encT = (const float*)d_in[0];
  const float* encI = (const float*)d_in[1];
  const float* mask = (const float*)d_in[2];
  const float* Wq   = (const float*)d_in[3];
  const float* bq   = (const float*)d_in[4];
  const float* Wk   = (const float*)d_in[5];
  const float* bk   = (const float*)d_in[6];
  const float* w    = (const float*)d_in[7];
  const float* bsc  = (const float*)d_in[8];
  float* out = (float*)d_out;

  float* q = (float*)d_ws;                 // [512, 512] f32, CTANH-prescaled
  float* k = q + (size_t)B_ * T_ * P_;     // [800, 512] f32, CTANH-prescaled

  // Both GEMMs in one launch: grid.y 0..7 -> Q (8 row tiles), 8..20 -> K (13)
  dim3 grid(N_ / 64, 8 + 13);
  mfma_linear_gelu<<<grid, 256, 0, stream>>>(encT, Wq, bq, q, encI, Wk, bk, k);

  fuse_kernel<<<dim3(512, 2), 256, 0, stream>>>(q, k, w, bsc, mask, out);
}